// Round 5
// baseline (817.309 us; speedup 1.0000x reference)
//
#include <hip/hip_runtime.h>
#include <hip/hip_bf16.h>
#include <cstdint>

#define HID 256
#define NGRAPH 16
#define NEG_SLOPE 0.01f

typedef __bf16 bf16x8 __attribute__((ext_vector_type(8)));
typedef float f32x4 __attribute__((ext_vector_type(4)));

__device__ __forceinline__ float leaky(float x) { return x >= 0.f ? x : NEG_SLOPE * x; }

__device__ __forceinline__ ushort f2b(float f) {
  uint u = __float_as_uint(f);
  uint r = (u + 0x7fffu + ((u >> 16) & 1u)) >> 16;
  return (ushort)r;
}
__device__ __forceinline__ float b2f(ushort b) { return __uint_as_float((uint)b << 16); }

// ---------------- CSR build ----------------
__global__ __launch_bounds__(256) void k_zero_i32(int* p, int n) {
  int i = blockIdx.x * blockDim.x + threadIdx.x;
  if (i < n) p[i] = 0;
}

__global__ __launch_bounds__(256) void k_hist(const int* __restrict__ key, int* __restrict__ cnt, int ne) {
  int e = blockIdx.x * blockDim.x + threadIdx.x;
  if (e < ne) atomicAdd(&cnt[key[e]], 1);
}

__global__ __launch_bounds__(1024) void k_scan(const int* __restrict__ cnt, int* __restrict__ rowptr,
                                               int* __restrict__ cursor, int n) {
  __shared__ int sd[1024];
  int tid = threadIdx.x;
  int CH = n / 1024 + 1;
  int base = tid * CH;
  int s = 0;
  for (int i = 0; i < CH; ++i) { int idx = base + i; if (idx < n) s += cnt[idx]; }
  sd[tid] = s;
  __syncthreads();
  for (int off = 1; off < 1024; off <<= 1) {
    int v = (tid >= off) ? sd[tid - off] : 0;
    __syncthreads();
    sd[tid] += v;
    __syncthreads();
  }
  int run = (tid == 0) ? 0 : sd[tid - 1];
  for (int i = 0; i < CH; ++i) {
    int idx = base + i;
    if (idx <= n) {
      rowptr[idx] = run;
      if (idx < n) { cursor[idx] = run; run += cnt[idx]; }
    }
  }
}

// batch sorted -> per-graph bounds via binary search
__global__ __launch_bounds__(64) void k_gbounds(const int* __restrict__ batch, int n,
                                                int* __restrict__ gstart, int* __restrict__ gcnt) {
  int t = threadIdx.x;
  if (t <= NGRAPH) {
    int lo = 0, hi = n;
    while (lo < hi) { int mid = (lo + hi) >> 1; if (batch[mid] < t) lo = mid + 1; else hi = mid; }
    gstart[t] = lo;
  }
  __syncthreads();
  if (t < NGRAPH) gcnt[t] = gstart[t + 1] - gstart[t];
}

__global__ __launch_bounds__(256) void k_scatter(const int* __restrict__ src, const int* __restrict__ dst,
                                                 int* __restrict__ cursor, int* __restrict__ col, int ne) {
  int e = blockIdx.x * blockDim.x + threadIdx.x;
  if (e < ne) {
    int d = dst[e];
    int pos = atomicAdd(&cursor[d], 1);
    col[pos] = src[e];
  }
}

// ---------------- conversions ----------------
__global__ __launch_bounds__(256) void k_f2b(const float* __restrict__ src, ushort* __restrict__ dst, int nElem) {
  int i = (blockIdx.x * 256 + threadIdx.x) * 4;
  if (i + 3 < nElem) {
    float4 v = *(const float4*)&src[i];
    ushort4 o;
    o.x = f2b(v.x); o.y = f2b(v.y); o.z = f2b(v.z); o.w = f2b(v.w);
    *(ushort4*)&dst[i] = o;
  } else {
    for (int j = i; j < nElem; ++j) dst[j] = f2b(src[j]);
  }
}

// fused transpose-convert for all weight matrices: dst[n][k] = bf16(src[k][n]); src is [K][256]
struct WconvArgs {
  const float* src[9];
  ushort* dst[9];
  int K[9];
};

__global__ __launch_bounds__(256) void k_wconv_all(WconvArgs args) {
  __shared__ float t[32][33];
  const int e = blockIdx.z;
  const int K = args.K[e];
  const int k0 = blockIdx.x * 32;
  if (k0 >= K) return;
  const float* src = args.src[e];
  ushort* dst = args.dst[e];
  const int n0 = blockIdx.y * 32;
  const int tx = threadIdx.x & 31;
  const int ty = threadIdx.x >> 5;
#pragma unroll
  for (int r = 0; r < 4; ++r) t[ty + 8 * r][tx] = src[(size_t)(k0 + ty + 8 * r) * 256 + n0 + tx];
  __syncthreads();
#pragma unroll
  for (int r = 0; r < 4; ++r) dst[(size_t)(n0 + ty + 8 * r) * K + k0 + tx] = f2b(t[tx][ty + 8 * r]);
}

// ---------------- aggregation: S=self+neighbors (bf16), hd=deg*self (bf16), degf ----------------
__global__ __launch_bounds__(256) void k_aggregate(const ushort* __restrict__ h, const int* __restrict__ rowptr,
                                                   const int* __restrict__ col, ushort* __restrict__ S,
                                                   ushort* __restrict__ hd, float* __restrict__ degf, int n) {
  int node = blockIdx.x * 4 + (threadIdx.x >> 6);
  if (node >= n) return;
  int lane = threadIdx.x & 63;
  const ushort4* h4 = (const ushort4*)h;
  size_t base = (size_t)node * 64 + lane;
  ushort4 self = h4[base];
  float a0 = b2f(self.x), a1 = b2f(self.y), a2 = b2f(self.z), a3 = b2f(self.w);
  float s0 = a0, s1 = a1, s2 = a2, s3 = a3;
  int beg = rowptr[node], end = rowptr[node + 1];
  int p = beg;
  // 4-way unroll: independent gather loads for latency hiding
  for (; p + 4 <= end; p += 4) {
    int j0 = col[p], j1 = col[p + 1], j2 = col[p + 2], j3 = col[p + 3];
    ushort4 v0 = h4[(size_t)j0 * 64 + lane];
    ushort4 v1 = h4[(size_t)j1 * 64 + lane];
    ushort4 v2 = h4[(size_t)j2 * 64 + lane];
    ushort4 v3 = h4[(size_t)j3 * 64 + lane];
    s0 += b2f(v0.x) + b2f(v1.x) + b2f(v2.x) + b2f(v3.x);
    s1 += b2f(v0.y) + b2f(v1.y) + b2f(v2.y) + b2f(v3.y);
    s2 += b2f(v0.z) + b2f(v1.z) + b2f(v2.z) + b2f(v3.z);
    s3 += b2f(v0.w) + b2f(v1.w) + b2f(v2.w) + b2f(v3.w);
  }
  for (; p < end; ++p) {
    int j = col[p];
    ushort4 v = h4[(size_t)j * 64 + lane];
    s0 += b2f(v.x); s1 += b2f(v.y); s2 += b2f(v.z); s3 += b2f(v.w);
  }
  float deg = (float)(end - beg + 1);
  ushort4 so; so.x = f2b(s0); so.y = f2b(s1); so.z = f2b(s2); so.w = f2b(s3);
  ((ushort4*)S)[base] = so;
  ushort4 ho; ho.x = f2b(deg * a0); ho.y = f2b(deg * a1); ho.z = f2b(deg * a2); ho.w = f2b(deg * a3);
  ((ushort4*)hd)[base] = ho;
  if (lane == 0) degf[node] = deg;
}

// ---------------- bf16 MFMA GEMM, no-LDS direct-fragment version ----------------
// C = act( A0@W0t^T (+ A1@W1t^T) + rs.*bias ), N=256 fixed.
// A: [M][K] bf16 row-major. Wt: [256][ldw] bf16 (transposed weights).
// tile 128x64, 4 waves (2x2: wave tile 64x32). Fragments loaded global->VGPR directly
// (weights + activations are L2-resident; K<=256 fully unrolled => deep load ILP, no barriers).
template <int K, int NPASS>
__global__ __launch_bounds__(256) void k_gemm_bf16(
    const ushort* __restrict__ A0, const ushort* __restrict__ W0t, int ldw0,
    const ushort* __restrict__ A1, const ushort* __restrict__ W1t, int ldw1,
    const float* __restrict__ bias, const float* __restrict__ rowscale,
    ushort* __restrict__ C, int M, int act)
{
  // bijective XCD-chunked remap (m204): 4 consecutive n-tiles (same A-panel) -> same XCD
  const int nwg = gridDim.x;
  const int q = nwg >> 3, r = nwg & 7;
  const int orig = blockIdx.x;
  const int xcd = orig & 7, base_i = orig >> 3;
  const int wgid = (xcd < r ? xcd * (q + 1) : r * (q + 1) + (xcd - r) * q) + base_i;
  const int mi = wgid >> 2;
  const int ni = wgid & 3;

  const int tid = threadIdx.x;
  const int lane = tid & 63;
  const int wid = tid >> 6;
  const int wm = wid >> 1;   // rows [wm*64, +64)
  const int wn = wid & 1;    // cols [wn*32, +32)
  const int rl = lane & 15;
  const int kg = lane >> 4;  // k-group 0..3 (8 contig bf16)
  const int m0 = mi * 128;
  const int n0 = ni * 64;
  constexpr int KS = K >> 5;

  f32x4 acc[4][2];
#pragma unroll
  for (int i = 0; i < 4; ++i)
#pragma unroll
    for (int j = 0; j < 2; ++j) acc[i][j] = (f32x4)(0.f);

  int arow[4], brow[2];
#pragma unroll
  for (int fm = 0; fm < 4; ++fm) {
    int rr = m0 + wm * 64 + fm * 16 + rl;
    arow[fm] = rr < M ? rr : M - 1;  // clamp: dup row, epilogue guards
  }
#pragma unroll
  for (int fn = 0; fn < 2; ++fn) brow[fn] = n0 + wn * 32 + fn * 16 + rl;
  const int kofs = kg * 8;

#pragma unroll
  for (int p = 0; p < NPASS; ++p) {
    const ushort* __restrict__ Ap = (p == 0) ? A0 : A1;
    const ushort* __restrict__ Wp = (p == 0) ? W0t : W1t;
    const int ldw = (p == 0) ? ldw0 : ldw1;

    const ushort* pa[4];
    const ushort* pb[2];
#pragma unroll
    for (int fm = 0; fm < 4; ++fm) pa[fm] = Ap + (size_t)arow[fm] * K + kofs;
#pragma unroll
    for (int fn = 0; fn < 2; ++fn) pb[fn] = Wp + (size_t)brow[fn] * ldw + kofs;

    bf16x8 af[2][4], bf_[2][2];
#pragma unroll
    for (int fm = 0; fm < 4; ++fm) af[0][fm] = *(const bf16x8*)(pa[fm]);
#pragma unroll
    for (int fn = 0; fn < 2; ++fn) bf_[0][fn] = *(const bf16x8*)(pb[fn]);

#pragma unroll
    for (int t = 0; t < KS; ++t) {
      const int cur = t & 1, nxt = cur ^ 1;
      if (t + 1 < KS) {
#pragma unroll
        for (int fm = 0; fm < 4; ++fm) af[nxt][fm] = *(const bf16x8*)(pa[fm] + (t + 1) * 32);
#pragma unroll
        for (int fn = 0; fn < 2; ++fn) bf_[nxt][fn] = *(const bf16x8*)(pb[fn] + (t + 1) * 32);
      }
#pragma unroll
      for (int fm = 0; fm < 4; ++fm)
#pragma unroll
        for (int fn = 0; fn < 2; ++fn)
          acc[fm][fn] = __builtin_amdgcn_mfma_f32_16x16x32_bf16(af[cur][fm], bf_[cur][fn], acc[fm][fn], 0, 0, 0);
    }
  }

  // epilogue: C/D layout col=lane&15, row=(lane>>4)*4+reg  [m89/m91]
  const int colb = n0 + wn * 32;
#pragma unroll
  for (int fm = 0; fm < 4; ++fm) {
    int row0 = m0 + wm * 64 + fm * 16 + kg * 4;
#pragma unroll
    for (int fn = 0; fn < 2; ++fn) {
      int c = colb + fn * 16 + rl;
      float bv = bias[c];
#pragma unroll
      for (int rg = 0; rg < 4; ++rg) {
        int row = row0 + rg;
        if (row < M) {
          float rs = rowscale ? rowscale[row] : 1.0f;
          float v = acc[fm][fn][rg] + rs * bv;
          if (act) v = leaky(v);
          C[(size_t)row * 256 + c] = f2b(v);
        }
      }
    }
  }
}

// ---------------- decoder layer ----------------
__global__ __launch_bounds__(256) void k_dec_layer(
    const float* __restrict__ A, const float* __restrict__ W,
    const float* __restrict__ bias, float* __restrict__ out,
    int K, int N, int act)
{
  __shared__ float a[768];
  __shared__ float red[8][64];
  const int g = blockIdx.y;
  const int cols = (N >= 64) ? 64 : 32;
  const int segs = 256 / cols;
  const int t = threadIdx.x;
  const int col = t % cols, seg = t / cols;
  const int c = blockIdx.x * cols + col;
  for (int i = t; i < K; i += 256) a[i] = A[(size_t)g * K + i];
  __syncthreads();
  const int kper = K / segs;
  const int k0 = seg * kper;
  float p = 0.f;
#pragma unroll 8
  for (int k = k0; k < k0 + kper; ++k) p += a[k] * W[(size_t)k * N + c];
  red[seg][col] = p;
  __syncthreads();
  if (seg == 0) {
    float s = bias[c];
    for (int i = 0; i < segs; ++i) s += red[i][col];
    out[(size_t)g * N + c] = act ? leaky(s) : s;
  }
}

// ---------------- pooling ----------------
__global__ __launch_bounds__(256) void k_pool1(const ushort* __restrict__ h, const int* __restrict__ gstart,
                                               const int* __restrict__ gcnt, float* __restrict__ psum,
                                               float* __restrict__ pmax) {
  int g = blockIdx.x >> 4;
  int cch = blockIdx.x & 15;
  int t = threadIdx.x;
  int len = gcnt[g];
  int s0 = gstart[g];
  int chunk = (len + 15) >> 4;
  int i0 = s0 + cch * chunk;
  int i1 = min(i0 + chunk, s0 + len);
  float s = 0.f;
  float m = -3.402823466e+38f;
  for (int i = i0; i < i1; ++i) {
    float v = b2f(h[(size_t)i * HID + t]);
    s += v;
    m = fmaxf(m, v);
  }
  psum[(size_t)blockIdx.x * HID + t] = s;
  pmax[(size_t)blockIdx.x * HID + t] = m;
}

__global__ __launch_bounds__(256) void k_pool2(const float* __restrict__ psum, const float* __restrict__ pmax,
                                               const int* __restrict__ gcnt, float* __restrict__ pooled) {
  int g = blockIdx.x;
  int t = threadIdx.x;
  float s = 0.f, m = -3.402823466e+38f;
  for (int cch = 0; cch < 16; ++cch) {
    s += psum[(size_t)(g * 16 + cch) * HID + t];
    m = fmaxf(m, pmax[(size_t)(g * 16 + cch) * HID + t]);
  }
  float cf = (float)gcnt[g];
  pooled[g * 3 * HID + t] = s / fmaxf(cf, 1.f);
  pooled[g * 3 * HID + HID + t] = m;
  pooled[g * 3 * HID + 2 * HID + t] = s;
}

// ---------------- launch ----------------
extern "C" void kernel_launch(void* const* d_in, const int* in_sizes, int n_in,
                              void* d_out, int out_size, void* d_ws, size_t ws_size,
                              hipStream_t stream) {
  const float* x        = (const float*)d_in[0];
  const int*   ei       = (const int*)d_in[1];
  const int*   batch    = (const int*)d_in[2];
  const float* enc_Win  = (const float*)d_in[3];
  const float* enc_bin  = (const float*)d_in[4];
  const float* enc_Wh   = (const float*)d_in[5];
  const float* enc_bh   = (const float*)d_in[6];
  const float* enc_Wout = (const float*)d_in[7];
  const float* enc_bout = (const float*)d_in[8];
  const float* edge_W   = (const float*)d_in[9];
  const float* edge_b   = (const float*)d_in[10];
  const float* proc_Win = (const float*)d_in[11];
  const float* proc_bin = (const float*)d_in[12];
  const float* proc_Wh  = (const float*)d_in[13];
  const float* proc_bh  = (const float*)d_in[14];
  const float* proc_Wout= (const float*)d_in[15];
  const float* proc_bout= (const float*)d_in[16];
  const float* dec_Win  = (const float*)d_in[17];
  const float* dec_bin  = (const float*)d_in[18];
  const float* dec_Wh   = (const float*)d_in[19];
  const float* dec_bh   = (const float*)d_in[20];
  const float* dec_Wout = (const float*)d_in[21];
  const float* dec_bout = (const float*)d_in[22];

  const int n  = in_sizes[0] / 128;  // 20000
  const int ne = in_sizes[1] / 2;    // 160000
  const int H = HID;

  char* p = (char*)d_ws;
  auto alloc = [&](size_t bytes) -> char* {
    char* r = p;
    p += (bytes + 255) & ~(size_t)255;
    return r;
  };
  ushort* hb0   = (ushort*)alloc((size_t)n * H * 2);
  ushort* hb1   = (ushort*)alloc((size_t)n * H * 2);
  ushort* Sb    = (ushort*)alloc((size_t)n * H * 2);
  ushort* hdb   = (ushort*)alloc((size_t)n * H * 2);
  ushort* xb    = (ushort*)alloc((size_t)n * 128 * 2);
  ushort* w_enc_in  = (ushort*)alloc((size_t)256 * 128 * 2);
  ushort* w_enc_h0  = (ushort*)alloc((size_t)256 * 256 * 2);
  ushort* w_enc_h1  = (ushort*)alloc((size_t)256 * 256 * 2);
  ushort* w_enc_out = (ushort*)alloc((size_t)256 * 256 * 2);
  ushort* w_proc_in  = (ushort*)alloc((size_t)256 * 256 * 2);
  ushort* w_proc_h0  = (ushort*)alloc((size_t)256 * 256 * 2);
  ushort* w_proc_h1  = (ushort*)alloc((size_t)256 * 256 * 2);
  ushort* w_proc_out = (ushort*)alloc((size_t)256 * 256 * 2);
  ushort* w_edge     = (ushort*)alloc((size_t)256 * 512 * 2);
  float* degf   = (float*)alloc((size_t)n * 4);
  float* pooled = (float*)alloc((size_t)NGRAPH * 3 * H * 4);
  float* psum   = (float*)alloc((size_t)256 * H * 4);
  float* pmax   = (float*)alloc((size_t)256 * H * 4);
  float* db0    = (float*)alloc((size_t)NGRAPH * H * 4);
  float* db1    = (float*)alloc((size_t)NGRAPH * H * 4);
  int* cnt    = (int*)alloc((size_t)n * 4);
  int* rowptr = (int*)alloc((size_t)(n + 1) * 4);
  int* cursor = (int*)alloc((size_t)n * 4);
  int* gstart = (int*)alloc((size_t)(NGRAPH + 1) * 4);
  int* gcnt   = (int*)alloc((size_t)NGRAPH * 4);
  int* colv   = (int*)alloc((size_t)ne * 4);

  const int* srcI = ei;
  const int* dstI = ei + ne;

  dim3 blk(256);

  // fused weight conversions (transpose to [N=256][K] bf16)
  WconvArgs wa;
  wa.src[0] = enc_Win;             wa.dst[0] = w_enc_in;   wa.K[0] = 128;
  wa.src[1] = enc_Wh;              wa.dst[1] = w_enc_h0;   wa.K[1] = 256;
  wa.src[2] = enc_Wh + 65536;      wa.dst[2] = w_enc_h1;   wa.K[2] = 256;
  wa.src[3] = enc_Wout;            wa.dst[3] = w_enc_out;  wa.K[3] = 256;
  wa.src[4] = proc_Win;            wa.dst[4] = w_proc_in;  wa.K[4] = 256;
  wa.src[5] = proc_Wh;             wa.dst[5] = w_proc_h0;  wa.K[5] = 256;
  wa.src[6] = proc_Wh + 65536;     wa.dst[6] = w_proc_h1;  wa.K[6] = 256;
  wa.src[7] = proc_Wout;           wa.dst[7] = w_proc_out; wa.K[7] = 256;
  wa.src[8] = edge_W;              wa.dst[8] = w_edge;     wa.K[8] = 512;
  k_wconv_all<<<dim3(16, 8, 9), blk, 0, stream>>>(wa);
  k_f2b<<<dim3((n * 128 / 4 + 255) / 256), blk, 0, stream>>>(x, xb, n * 128);

  // CSR by destination + per-graph bounds
  k_zero_i32<<<dim3((n + 255) / 256), blk, 0, stream>>>(cnt, n);
  k_hist<<<dim3((ne + 255) / 256), blk, 0, stream>>>(dstI, cnt, ne);
  k_scan<<<1, 1024, 0, stream>>>(cnt, rowptr, cursor, n);
  k_gbounds<<<1, 64, 0, stream>>>(batch, n, gstart, gcnt);
  k_scatter<<<dim3((ne + 255) / 256), blk, 0, stream>>>(srcI, dstI, cursor, colv, ne);

  const int nwg = ((n + 127) / 128) * 4;  // 628
  dim3 gg(nwg);

  // encoder
  k_gemm_bf16<128, 1><<<gg, blk, 0, stream>>>(xb,  w_enc_in, 128, nullptr, nullptr, 0, enc_bin,      nullptr, hb0, n, 1);
  k_gemm_bf16<256, 1><<<gg, blk, 0, stream>>>(hb0, w_enc_h0, 256, nullptr, nullptr, 0, enc_bh,       nullptr, hb1, n, 1);
  k_gemm_bf16<256, 1><<<gg, blk, 0, stream>>>(hb1, w_enc_h1, 256, nullptr, nullptr, 0, enc_bh + 256, nullptr, hb0, n, 1);
  k_gemm_bf16<256, 1><<<gg, blk, 0, stream>>>(hb0, w_enc_out, 256, nullptr, nullptr, 0, enc_bout,    nullptr, hb1, n, 0);

  // 4 message-passing rounds; h in hb1 at loop head
  for (int r = 0; r < 4; ++r) {
    k_aggregate<<<dim3((n + 3) / 4), blk, 0, stream>>>(hb1, rowptr, colv, Sb, hdb, degf, n);
    // agg = (deg.*h)@W1 + S@W2 + deg.*edge_b
    k_gemm_bf16<256, 2><<<gg, blk, 0, stream>>>(hdb, w_edge, 512, Sb, w_edge + 256, 512, edge_b, degf, hb0, n, 0);
    // proc MLP
    k_gemm_bf16<256, 1><<<gg, blk, 0, stream>>>(hb0, w_proc_in, 256, nullptr, nullptr, 0, proc_bin,      nullptr, Sb,  n, 1);
    k_gemm_bf16<256, 1><<<gg, blk, 0, stream>>>(Sb,  w_proc_h0, 256, nullptr, nullptr, 0, proc_bh,       nullptr, hb0, n, 1);
    k_gemm_bf16<256, 1><<<gg, blk, 0, stream>>>(hb0, w_proc_h1, 256, nullptr, nullptr, 0, proc_bh + 256, nullptr, Sb,  n, 1);
    k_gemm_bf16<256, 1><<<gg, blk, 0, stream>>>(Sb,  w_proc_out, 256, nullptr, nullptr, 0, proc_bout,    nullptr, hb1, n, 0);
  }

  // pooling
  k_pool1<<<dim3(NGRAPH * 16), blk, 0, stream>>>(hb1, gstart, gcnt, psum, pmax);
  k_pool2<<<dim3(NGRAPH), blk, 0, stream>>>(psum, pmax, gcnt, pooled);

  // decoder
  k_dec_layer<<<dim3(4, NGRAPH), blk, 0, stream>>>(pooled, dec_Win, dec_bin, db0, 768, 256, 1);
  k_dec_layer<<<dim3(4, NGRAPH), blk, 0, stream>>>(db0, dec_Wh, dec_bh, db1, 256, 256, 1);
  k_dec_layer<<<dim3(4, NGRAPH), blk, 0, stream>>>(db1, dec_Wh + 65536, dec_bh + 256, db0, 256, 256, 1);
  k_dec_layer<<<dim3(1, NGRAPH), blk, 0, stream>>>(db0, dec_Wout, dec_bout, (float*)d_out, 256, 32, 0);
}

// Round 6
// 487.754 us; speedup vs baseline: 1.6757x; 1.6757x over previous
//
#include <hip/hip_runtime.h>
#include <hip/hip_bf16.h>
#include <cstdint>

#define HID 256
#define NGRAPH 16
#define NEG_SLOPE 0.01f

typedef __bf16 bf16x8 __attribute__((ext_vector_type(8)));
typedef float f32x4 __attribute__((ext_vector_type(4)));

__device__ __forceinline__ float leaky(float x) { return x >= 0.f ? x : NEG_SLOPE * x; }

__device__ __forceinline__ ushort f2b(float f) {
  uint u = __float_as_uint(f);
  uint r = (u + 0x7fffu + ((u >> 16) & 1u)) >> 16;
  return (ushort)r;
}
__device__ __forceinline__ float b2f(ushort b) { return __uint_as_float((uint)b << 16); }

// ---------------- CSR build ----------------
__global__ __launch_bounds__(256) void k_zero_i32(int* p, int n) {
  int i = blockIdx.x * blockDim.x + threadIdx.x;
  if (i < n) p[i] = 0;
}

__global__ __launch_bounds__(256) void k_hist(const int* __restrict__ key, int* __restrict__ cnt, int ne) {
  int e = blockIdx.x * blockDim.x + threadIdx.x;
  if (e < ne) atomicAdd(&cnt[key[e]], 1);
}

__global__ __launch_bounds__(1024) void k_scan(const int* __restrict__ cnt, int* __restrict__ rowptr,
                                               int* __restrict__ cursor, int n) {
  __shared__ int sd[1024];
  int tid = threadIdx.x;
  int CH = n / 1024 + 1;
  int base = tid * CH;
  int s = 0;
  for (int i = 0; i < CH; ++i) { int idx = base + i; if (idx < n) s += cnt[idx]; }
  sd[tid] = s;
  __syncthreads();
  for (int off = 1; off < 1024; off <<= 1) {
    int v = (tid >= off) ? sd[tid - off] : 0;
    __syncthreads();
    sd[tid] += v;
    __syncthreads();
  }
  int run = (tid == 0) ? 0 : sd[tid - 1];
  for (int i = 0; i < CH; ++i) {
    int idx = base + i;
    if (idx <= n) {
      rowptr[idx] = run;
      if (idx < n) { cursor[idx] = run; run += cnt[idx]; }
    }
  }
}

// batch sorted -> per-graph bounds via binary search
__global__ __launch_bounds__(64) void k_gbounds(const int* __restrict__ batch, int n,
                                                int* __restrict__ gstart, int* __restrict__ gcnt) {
  int t = threadIdx.x;
  if (t <= NGRAPH) {
    int lo = 0, hi = n;
    while (lo < hi) { int mid = (lo + hi) >> 1; if (batch[mid] < t) lo = mid + 1; else hi = mid; }
    gstart[t] = lo;
  }
  __syncthreads();
  if (t < NGRAPH) gcnt[t] = gstart[t + 1] - gstart[t];
}

__global__ __launch_bounds__(256) void k_scatter(const int* __restrict__ src, const int* __restrict__ dst,
                                                 int* __restrict__ cursor, int* __restrict__ col, int ne) {
  int e = blockIdx.x * blockDim.x + threadIdx.x;
  if (e < ne) {
    int d = dst[e];
    int pos = atomicAdd(&cursor[d], 1);
    col[pos] = src[e];
  }
}

// ---------------- conversions ----------------
__global__ __launch_bounds__(256) void k_f2b(const float* __restrict__ src, ushort* __restrict__ dst, int nElem) {
  int i = (blockIdx.x * 256 + threadIdx.x) * 4;
  if (i + 3 < nElem) {
    float4 v = *(const float4*)&src[i];
    ushort4 o;
    o.x = f2b(v.x); o.y = f2b(v.y); o.z = f2b(v.z); o.w = f2b(v.w);
    *(ushort4*)&dst[i] = o;
  } else {
    for (int j = i; j < nElem; ++j) dst[j] = f2b(src[j]);
  }
}

// fused transpose-convert for all weight matrices: dst[n][k] = bf16(src[k][n]); src is [K][256]
struct WconvArgs {
  const float* src[9];
  ushort* dst[9];
  int K[9];
};

__global__ __launch_bounds__(256) void k_wconv_all(WconvArgs args) {
  __shared__ float t[32][33];
  const int e = blockIdx.z;
  const int K = args.K[e];
  const int k0 = blockIdx.x * 32;
  if (k0 >= K) return;
  const float* src = args.src[e];
  ushort* dst = args.dst[e];
  const int n0 = blockIdx.y * 32;
  const int tx = threadIdx.x & 31;
  const int ty = threadIdx.x >> 5;
#pragma unroll
  for (int r = 0; r < 4; ++r) t[ty + 8 * r][tx] = src[(size_t)(k0 + ty + 8 * r) * 256 + n0 + tx];
  __syncthreads();
#pragma unroll
  for (int r = 0; r < 4; ++r) dst[(size_t)(n0 + ty + 8 * r) * K + k0 + tx] = f2b(t[tx][ty + 8 * r]);
}

// ---------------- aggregation: S=self+neighbors (bf16), hd=deg*self (bf16), degf ----------------
__global__ __launch_bounds__(256) void k_aggregate(const ushort* __restrict__ h, const int* __restrict__ rowptr,
                                                   const int* __restrict__ col, ushort* __restrict__ S,
                                                   ushort* __restrict__ hd, float* __restrict__ degf, int n) {
  int node = blockIdx.x * 4 + (threadIdx.x >> 6);
  if (node >= n) return;
  int lane = threadIdx.x & 63;
  const ushort4* h4 = (const ushort4*)h;
  size_t base = (size_t)node * 64 + lane;
  ushort4 self = h4[base];
  float a0 = b2f(self.x), a1 = b2f(self.y), a2 = b2f(self.z), a3 = b2f(self.w);
  float s0 = a0, s1 = a1, s2 = a2, s3 = a3;
  int beg = rowptr[node], end = rowptr[node + 1];
  int p = beg;
  for (; p + 4 <= end; p += 4) {
    int j0 = col[p], j1 = col[p + 1], j2 = col[p + 2], j3 = col[p + 3];
    ushort4 v0 = h4[(size_t)j0 * 64 + lane];
    ushort4 v1 = h4[(size_t)j1 * 64 + lane];
    ushort4 v2 = h4[(size_t)j2 * 64 + lane];
    ushort4 v3 = h4[(size_t)j3 * 64 + lane];
    s0 += b2f(v0.x) + b2f(v1.x) + b2f(v2.x) + b2f(v3.x);
    s1 += b2f(v0.y) + b2f(v1.y) + b2f(v2.y) + b2f(v3.y);
    s2 += b2f(v0.z) + b2f(v1.z) + b2f(v2.z) + b2f(v3.z);
    s3 += b2f(v0.w) + b2f(v1.w) + b2f(v2.w) + b2f(v3.w);
  }
  for (; p < end; ++p) {
    int j = col[p];
    ushort4 v = h4[(size_t)j * 64 + lane];
    s0 += b2f(v.x); s1 += b2f(v.y); s2 += b2f(v.z); s3 += b2f(v.w);
  }
  float deg = (float)(end - beg + 1);
  ushort4 so; so.x = f2b(s0); so.y = f2b(s1); so.z = f2b(s2); so.w = f2b(s3);
  ((ushort4*)S)[base] = so;
  ushort4 ho; ho.x = f2b(deg * a0); ho.y = f2b(deg * a1); ho.z = f2b(deg * a2); ho.w = f2b(deg * a3);
  ((ushort4*)hd)[base] = ho;
  if (lane == 0) degf[node] = deg;
}

// ---------------- bf16 MFMA GEMM: C = act( A0@W0t^T (+ A1@W1t^T) + rs.*bias ), N=256 fixed ----------------
// tile 128x64, 4 waves (2x2), wave tile 64x32, BK=32, double-buffered LDS.
// Staging: global_load_lds width=16, linear LDS dest (= wave base + lane*16), XOR k-slot
// swizzle applied on the PRE-SWIZZLED GLOBAL SOURCE address, same swizzle on ds_read (rule #21).
template <int K, int NPASS>
__global__ __launch_bounds__(256) void k_gemm_bf16(
    const ushort* __restrict__ A0, const ushort* __restrict__ W0t, int ldw0,
    const ushort* __restrict__ A1, const ushort* __restrict__ W1t, int ldw1,
    const float* __restrict__ bias, const float* __restrict__ rowscale,
    ushort* __restrict__ C, int M, int act)
{
  __shared__ __align__(16) ushort lds[2][128 * 32 + 64 * 32];  // 12 KB per buffer
  // bijective XCD-chunked remap (m204): 4 consecutive n-tiles (same A-panel) -> same XCD
  const int nwg = gridDim.x;
  const int q = nwg >> 3, r = nwg & 7;
  const int orig = blockIdx.x;
  const int xcd = orig & 7, base_i = orig >> 3;
  const int wgid = (xcd < r ? xcd * (q + 1) : r * (q + 1) + (xcd - r) * q) + base_i;
  const int mi = wgid >> 2;
  const int ni = wgid & 3;

  const int tid = threadIdx.x;
  const int lane = tid & 63;
  const int wid = tid >> 6;
  const int wm = wid >> 1;   // rows [wm*64, +64)
  const int wn = wid & 1;    // cols [wn*32, +32)
  const int rl = lane & 15;
  const int kg = lane >> 4;  // k-group 0..3 (8 contig bf16)
  const int m0 = mi * 128;
  const int n0 = ni * 64;
  constexpr int KS = K >> 5;
  constexpr int NT = NPASS * KS;

  f32x4 acc[4][2];
#pragma unroll
  for (int i = 0; i < 4; ++i)
#pragma unroll
    for (int j = 0; j < 2; ++j) acc[i][j] = (f32x4)(0.f);

  // staging slot s -> row=s>>2, sl=s&3; LDS (row,sl) holds global k-group (sl ^ ((row>>1)&3))
  const int a_row0 = tid >> 2, a_sl = tid & 3;
  const int a_row1 = (tid + 256) >> 2;
  const int a_kg0 = a_sl ^ ((a_row0 >> 1) & 3);
  const int a_kg1 = a_sl ^ ((a_row1 >> 1) & 3);
  const int b_row = tid >> 2, b_kg = a_sl ^ ((b_row >> 1) & 3);
  int ga0 = m0 + a_row0; if (ga0 > M - 1) ga0 = M - 1;
  int ga1 = m0 + a_row1; if (ga1 > M - 1) ga1 = M - 1;
  const int gb0 = n0 + b_row;

#define GLOAD(b, t)                                                                      \
  {                                                                                      \
    int p_ = (t) / KS;                                                                   \
    int k0_ = ((t) - p_ * KS) << 5;                                                      \
    const ushort* Ap_ = p_ ? A1 : A0;                                                    \
    const ushort* Wp_ = p_ ? W1t : W0t;                                                  \
    int ldw_ = p_ ? ldw1 : ldw0;                                                         \
    const ushort* sa0_ = Ap_ + (size_t)ga0 * K + k0_ + a_kg0 * 8;                        \
    const ushort* sa1_ = Ap_ + (size_t)ga1 * K + k0_ + a_kg1 * 8;                        \
    const ushort* sb_  = Wp_ + (size_t)gb0 * ldw_ + k0_ + b_kg * 8;                      \
    __builtin_amdgcn_global_load_lds(                                                    \
        (const __attribute__((address_space(1))) void*)sa0_,                             \
        (__attribute__((address_space(3))) void*)&lds[b][tid * 8], 16, 0, 0);            \
    __builtin_amdgcn_global_load_lds(                                                    \
        (const __attribute__((address_space(1))) void*)sa1_,                             \
        (__attribute__((address_space(3))) void*)&lds[b][(tid + 256) * 8], 16, 0, 0);    \
    __builtin_amdgcn_global_load_lds(                                                    \
        (const __attribute__((address_space(1))) void*)sb_,                              \
        (__attribute__((address_space(3))) void*)&lds[b][(tid + 512) * 8], 16, 0, 0);    \
  }

  GLOAD(0, 0);
  __syncthreads();

  for (int t = 0; t < NT; ++t) {
    if (t + 1 < NT) GLOAD((t + 1) & 1, t + 1);  // async, in flight through MFMA phase
    const ushort* bA = &lds[t & 1][0];
    const ushort* bB = &lds[t & 1][4096];
    bf16x8 af[4], bfr[2];
#pragma unroll
    for (int fm = 0; fm < 4; ++fm) {
      int rr = wm * 64 + fm * 16 + rl;
      int s = kg ^ ((rr >> 1) & 3);
      af[fm] = *(const bf16x8*)&bA[rr * 32 + s * 8];
    }
#pragma unroll
    for (int fn = 0; fn < 2; ++fn) {
      int rn = wn * 32 + fn * 16 + rl;
      int s = kg ^ ((rn >> 1) & 3);
      bfr[fn] = *(const bf16x8*)&bB[rn * 32 + s * 8];
    }
#pragma unroll
    for (int fm = 0; fm < 4; ++fm)
#pragma unroll
      for (int fn = 0; fn < 2; ++fn)
        acc[fm][fn] = __builtin_amdgcn_mfma_f32_16x16x32_bf16(af[fm], bfr[fn], acc[fm][fn], 0, 0, 0);
    __syncthreads();  // drains vmcnt (next-tile loads) + lgkm, releases buffers
  }
#undef GLOAD

  // epilogue: C/D layout col=lane&15, row=(lane>>4)*4+reg  [m89/m91]
  const int colb = n0 + wn * 32;
#pragma unroll
  for (int fm = 0; fm < 4; ++fm) {
    int row0 = m0 + wm * 64 + fm * 16 + kg * 4;
#pragma unroll
    for (int fn = 0; fn < 2; ++fn) {
      int c = colb + fn * 16 + rl;
      float bv = bias[c];
#pragma unroll
      for (int rg = 0; rg < 4; ++rg) {
        int row = row0 + rg;
        if (row < M) {
          float rs = rowscale ? rowscale[row] : 1.0f;
          float v = acc[fm][fn][rg] + rs * bv;
          if (act) v = leaky(v);
          C[(size_t)row * 256 + c] = f2b(v);
        }
      }
    }
  }
}

// ---------------- decoder layer ----------------
__global__ __launch_bounds__(256) void k_dec_layer(
    const float* __restrict__ A, const float* __restrict__ W,
    const float* __restrict__ bias, float* __restrict__ out,
    int K, int N, int act)
{
  __shared__ float a[768];
  __shared__ float red[8][64];
  const int g = blockIdx.y;
  const int cols = (N >= 64) ? 64 : 32;
  const int segs = 256 / cols;
  const int t = threadIdx.x;
  const int col = t % cols, seg = t / cols;
  const int c = blockIdx.x * cols + col;
  for (int i = t; i < K; i += 256) a[i] = A[(size_t)g * K + i];
  __syncthreads();
  const int kper = K / segs;
  const int k0 = seg * kper;
  float p = 0.f;
#pragma unroll 8
  for (int k = k0; k < k0 + kper; ++k) p += a[k] * W[(size_t)k * N + c];
  red[seg][col] = p;
  __syncthreads();
  if (seg == 0) {
    float s = bias[c];
    for (int i = 0; i < segs; ++i) s += red[i][col];
    out[(size_t)g * N + c] = act ? leaky(s) : s;
  }
}

// ---------------- pooling ----------------
__global__ __launch_bounds__(256) void k_pool1(const ushort* __restrict__ h, const int* __restrict__ gstart,
                                               const int* __restrict__ gcnt, float* __restrict__ psum,
                                               float* __restrict__ pmax) {
  int g = blockIdx.x >> 4;
  int cch = blockIdx.x & 15;
  int t = threadIdx.x;
  int len = gcnt[g];
  int s0 = gstart[g];
  int chunk = (len + 15) >> 4;
  int i0 = s0 + cch * chunk;
  int i1 = min(i0 + chunk, s0 + len);
  float s = 0.f;
  float m = -3.402823466e+38f;
  for (int i = i0; i < i1; ++i) {
    float v = b2f(h[(size_t)i * HID + t]);
    s += v;
    m = fmaxf(m, v);
  }
  psum[(size_t)blockIdx.x * HID + t] = s;
  pmax[(size_t)blockIdx.x * HID + t] = m;
}

__global__ __launch_bounds__(256) void k_pool2(const float* __restrict__ psum, const float* __restrict__ pmax,
                                               const int* __restrict__ gcnt, float* __restrict__ pooled) {
  int g = blockIdx.x;
  int t = threadIdx.x;
  float s = 0.f, m = -3.402823466e+38f;
  for (int cch = 0; cch < 16; ++cch) {
    s += psum[(size_t)(g * 16 + cch) * HID + t];
    m = fmaxf(m, pmax[(size_t)(g * 16 + cch) * HID + t]);
  }
  float cf = (float)gcnt[g];
  pooled[g * 3 * HID + t] = s / fmaxf(cf, 1.f);
  pooled[g * 3 * HID + HID + t] = m;
  pooled[g * 3 * HID + 2 * HID + t] = s;
}

// ---------------- launch ----------------
extern "C" void kernel_launch(void* const* d_in, const int* in_sizes, int n_in,
                              void* d_out, int out_size, void* d_ws, size_t ws_size,
                              hipStream_t stream) {
  const float* x        = (const float*)d_in[0];
  const int*   ei       = (const int*)d_in[1];
  const int*   batch    = (const int*)d_in[2];
  const float* enc_Win  = (const float*)d_in[3];
  const float* enc_bin  = (const float*)d_in[4];
  const float* enc_Wh   = (const float*)d_in[5];
  const float* enc_bh   = (const float*)d_in[6];
  const float* enc_Wout = (const float*)d_in[7];
  const float* enc_bout = (const float*)d_in[8];
  const float* edge_W   = (const float*)d_in[9];
  const float* edge_b   = (const float*)d_in[10];
  const float* proc_Win = (const float*)d_in[11];
  const float* proc_bin = (const float*)d_in[12];
  const float* proc_Wh  = (const float*)d_in[13];
  const float* proc_bh  = (const float*)d_in[14];
  const float* proc_Wout= (const float*)d_in[15];
  const float* proc_bout= (const float*)d_in[16];
  const float* dec_Win  = (const float*)d_in[17];
  const float* dec_bin  = (const float*)d_in[18];
  const float* dec_Wh   = (const float*)d_in[19];
  const float* dec_bh   = (const float*)d_in[20];
  const float* dec_Wout = (const float*)d_in[21];
  const float* dec_bout = (const float*)d_in[22];

  const int n  = in_sizes[0] / 128;  // 20000
  const int ne = in_sizes[1] / 2;    // 160000
  const int H = HID;

  char* p = (char*)d_ws;
  auto alloc = [&](size_t bytes) -> char* {
    char* r = p;
    p += (bytes + 255) & ~(size_t)255;
    return r;
  };
  ushort* hb0   = (ushort*)alloc((size_t)n * H * 2);
  ushort* hb1   = (ushort*)alloc((size_t)n * H * 2);
  ushort* Sb    = (ushort*)alloc((size_t)n * H * 2);
  ushort* hdb   = (ushort*)alloc((size_t)n * H * 2);
  ushort* xb    = (ushort*)alloc((size_t)n * 128 * 2);
  ushort* w_enc_in  = (ushort*)alloc((size_t)256 * 128 * 2);
  ushort* w_enc_h0  = (ushort*)alloc((size_t)256 * 256 * 2);
  ushort* w_enc_h1  = (ushort*)alloc((size_t)256 * 256 * 2);
  ushort* w_enc_out = (ushort*)alloc((size_t)256 * 256 * 2);
  ushort* w_proc_in  = (ushort*)alloc((size_t)256 * 256 * 2);
  ushort* w_proc_h0  = (ushort*)alloc((size_t)256 * 256 * 2);
  ushort* w_proc_h1  = (ushort*)alloc((size_t)256 * 256 * 2);
  ushort* w_proc_out = (ushort*)alloc((size_t)256 * 256 * 2);
  ushort* w_edge     = (ushort*)alloc((size_t)256 * 512 * 2);
  float* degf   = (float*)alloc((size_t)n * 4);
  float* pooled = (float*)alloc((size_t)NGRAPH * 3 * H * 4);
  float* psum   = (float*)alloc((size_t)256 * H * 4);
  float* pmax   = (float*)alloc((size_t)256 * H * 4);
  float* db0    = (float*)alloc((size_t)NGRAPH * H * 4);
  float* db1    = (float*)alloc((size_t)NGRAPH * H * 4);
  int* cnt    = (int*)alloc((size_t)n * 4);
  int* rowptr = (int*)alloc((size_t)(n + 1) * 4);
  int* cursor = (int*)alloc((size_t)n * 4);
  int* gstart = (int*)alloc((size_t)(NGRAPH + 1) * 4);
  int* gcnt   = (int*)alloc((size_t)NGRAPH * 4);
  int* colv   = (int*)alloc((size_t)ne * 4);

  const int* srcI = ei;
  const int* dstI = ei + ne;

  dim3 blk(256);

  // fused weight conversions (transpose to [N=256][K] bf16)
  WconvArgs wa;
  wa.src[0] = enc_Win;             wa.dst[0] = w_enc_in;   wa.K[0] = 128;
  wa.src[1] = enc_Wh;              wa.dst[1] = w_enc_h0;   wa.K[1] = 256;
  wa.src[2] = enc_Wh + 65536;      wa.dst[2] = w_enc_h1;   wa.K[2] = 256;
  wa.src[3] = enc_Wout;            wa.dst[3] = w_enc_out;  wa.K[3] = 256;
  wa.src[4] = proc_Win;            wa.dst[4] = w_proc_in;  wa.K[4] = 256;
  wa.src[5] = proc_Wh;             wa.dst[5] = w_proc_h0;  wa.K[5] = 256;
  wa.src[6] = proc_Wh + 65536;     wa.dst[6] = w_proc_h1;  wa.K[6] = 256;
  wa.src[7] = proc_Wout;           wa.dst[7] = w_proc_out; wa.K[7] = 256;
  wa.src[8] = edge_W;              wa.dst[8] = w_edge;     wa.K[8] = 512;
  k_wconv_all<<<dim3(16, 8, 9), blk, 0, stream>>>(wa);
  k_f2b<<<dim3((n * 128 / 4 + 255) / 256), blk, 0, stream>>>(x, xb, n * 128);

  // CSR by destination + per-graph bounds
  k_zero_i32<<<dim3((n + 255) / 256), blk, 0, stream>>>(cnt, n);
  k_hist<<<dim3((ne + 255) / 256), blk, 0, stream>>>(dstI, cnt, ne);
  k_scan<<<1, 1024, 0, stream>>>(cnt, rowptr, cursor, n);
  k_gbounds<<<1, 64, 0, stream>>>(batch, n, gstart, gcnt);
  k_scatter<<<dim3((ne + 255) / 256), blk, 0, stream>>>(srcI, dstI, cursor, colv, ne);

  const int nwg = ((n + 127) / 128) * 4;  // 628
  dim3 gg(nwg);

  // encoder
  k_gemm_bf16<128, 1><<<gg, blk, 0, stream>>>(xb,  w_enc_in, 128, nullptr, nullptr, 0, enc_bin,      nullptr, hb0, n, 1);
  k_gemm_bf16<256, 1><<<gg, blk, 0, stream>>>(hb0, w_enc_h0, 256, nullptr, nullptr, 0, enc_bh,       nullptr, hb1, n, 1);
  k_gemm_bf16<256, 1><<<gg, blk, 0, stream>>>(hb1, w_enc_h1, 256, nullptr, nullptr, 0, enc_bh + 256, nullptr, hb0, n, 1);
  k_gemm_bf16<256, 1><<<gg, blk, 0, stream>>>(hb0, w_enc_out, 256, nullptr, nullptr, 0, enc_bout,    nullptr, hb1, n, 0);

  // 4 message-passing rounds; h in hb1 at loop head
  for (int r = 0; r < 4; ++r) {
    k_aggregate<<<dim3((n + 3) / 4), blk, 0, stream>>>(hb1, rowptr, colv, Sb, hdb, degf, n);
    // agg = (deg.*h)@W1 + S@W2 + deg.*edge_b
    k_gemm_bf16<256, 2><<<gg, blk, 0, stream>>>(hdb, w_edge, 512, Sb, w_edge + 256, 512, edge_b, degf, hb0, n, 0);
    // proc MLP
    k_gemm_bf16<256, 1><<<gg, blk, 0, stream>>>(hb0, w_proc_in, 256, nullptr, nullptr, 0, proc_bin,      nullptr, Sb,  n, 1);
    k_gemm_bf16<256, 1><<<gg, blk, 0, stream>>>(Sb,  w_proc_h0, 256, nullptr, nullptr, 0, proc_bh,       nullptr, hb0, n, 1);
    k_gemm_bf16<256, 1><<<gg, blk, 0, stream>>>(hb0, w_proc_h1, 256, nullptr, nullptr, 0, proc_bh + 256, nullptr, Sb,  n, 1);
    k_gemm_bf16<256, 1><<<gg, blk, 0, stream>>>(Sb,  w_proc_out, 256, nullptr, nullptr, 0, proc_bout,    nullptr, hb1, n, 0);
  }

  // pooling
  k_pool1<<<dim3(NGRAPH * 16), blk, 0, stream>>>(hb1, gstart, gcnt, psum, pmax);
  k_pool2<<<dim3(NGRAPH), blk, 0, stream>>>(psum, pmax, gcnt, pooled);

  // decoder
  k_dec_layer<<<dim3(4, NGRAPH), blk, 0, stream>>>(pooled, dec_Win, dec_bin, db0, 768, 256, 1);
  k_dec_layer<<<dim3(4, NGRAPH), blk, 0, stream>>>(db0, dec_Wh, dec_bh, db1, 256, 256, 1);
  k_dec_layer<<<dim3(4, NGRAPH), blk, 0, stream>>>(db1, dec_Wh + 65536, dec_bh + 256, db0, 256, 256, 1);
  k_dec_layer<<<dim3(1, NGRAPH), blk, 0, stream>>>(db0, dec_Wout, dec_bout, (float*)d_out, 256, 32, 0);
}

// Round 7
// 407.586 us; speedup vs baseline: 2.0052x; 1.1967x over previous
//
#include <hip/hip_runtime.h>
#include <hip/hip_bf16.h>
#include <cstdint>

#define HID 256
#define NGRAPH 16
#define NEG_SLOPE 0.01f

typedef __bf16 bf16x8 __attribute__((ext_vector_type(8)));
typedef float f32x4 __attribute__((ext_vector_type(4)));

__device__ __forceinline__ float leaky(float x) { return x >= 0.f ? x : NEG_SLOPE * x; }

__device__ __forceinline__ ushort f2b(float f) {
  uint u = __float_as_uint(f);
  uint r = (u + 0x7fffu + ((u >> 16) & 1u)) >> 16;
  return (ushort)r;
}
__device__ __forceinline__ float b2f(ushort b) { return __uint_as_float((uint)b << 16); }

// ---------------- CSR build ----------------
__global__ __launch_bounds__(256) void k_zero_i32(int* p, int n) {
  int i = blockIdx.x * blockDim.x + threadIdx.x;
  if (i < n) p[i] = 0;
}

__global__ __launch_bounds__(256) void k_hist(const int* __restrict__ key, int* __restrict__ cnt, int ne) {
  int e = blockIdx.x * blockDim.x + threadIdx.x;
  if (e < ne) atomicAdd(&cnt[key[e]], 1);
}

__global__ __launch_bounds__(1024) void k_scan(const int* __restrict__ cnt, int* __restrict__ rowptr,
                                               int* __restrict__ cursor, int n) {
  __shared__ int sd[1024];
  int tid = threadIdx.x;
  int CH = n / 1024 + 1;
  int base = tid * CH;
  int s = 0;
  for (int i = 0; i < CH; ++i) { int idx = base + i; if (idx < n) s += cnt[idx]; }
  sd[tid] = s;
  __syncthreads();
  for (int off = 1; off < 1024; off <<= 1) {
    int v = (tid >= off) ? sd[tid - off] : 0;
    __syncthreads();
    sd[tid] += v;
    __syncthreads();
  }
  int run = (tid == 0) ? 0 : sd[tid - 1];
  for (int i = 0; i < CH; ++i) {
    int idx = base + i;
    if (idx <= n) {
      rowptr[idx] = run;
      if (idx < n) { cursor[idx] = run; run += cnt[idx]; }
    }
  }
}

// batch sorted -> per-graph bounds via binary search
__global__ __launch_bounds__(64) void k_gbounds(const int* __restrict__ batch, int n,
                                                int* __restrict__ gstart, int* __restrict__ gcnt) {
  int t = threadIdx.x;
  if (t <= NGRAPH) {
    int lo = 0, hi = n;
    while (lo < hi) { int mid = (lo + hi) >> 1; if (batch[mid] < t) lo = mid + 1; else hi = mid; }
    gstart[t] = lo;
  }
  __syncthreads();
  if (t < NGRAPH) gcnt[t] = gstart[t + 1] - gstart[t];
}

__global__ __launch_bounds__(256) void k_scatter(const int* __restrict__ src, const int* __restrict__ dst,
                                                 int* __restrict__ cursor, int* __restrict__ col, int ne) {
  int e = blockIdx.x * blockDim.x + threadIdx.x;
  if (e < ne) {
    int d = dst[e];
    int pos = atomicAdd(&cursor[d], 1);
    col[pos] = src[e];
  }
}

// ---------------- conversions ----------------
__global__ __launch_bounds__(256) void k_f2b(const float* __restrict__ src, ushort* __restrict__ dst, int nElem) {
  int i = (blockIdx.x * 256 + threadIdx.x) * 4;
  if (i + 3 < nElem) {
    float4 v = *(const float4*)&src[i];
    ushort4 o;
    o.x = f2b(v.x); o.y = f2b(v.y); o.z = f2b(v.z); o.w = f2b(v.w);
    *(ushort4*)&dst[i] = o;
  } else {
    for (int j = i; j < nElem; ++j) dst[j] = f2b(src[j]);
  }
}

// fused transpose-convert: dst[n][k] = bf16(src[k][n]); src is [K][256]
struct WconvArgs {
  const float* src[9];
  ushort* dst[9];
  int K[9];
};

__global__ __launch_bounds__(256) void k_wconv_all(WconvArgs args) {
  __shared__ float t[32][33];
  const int e = blockIdx.z;
  const int K = args.K[e];
  const int k0 = blockIdx.x * 32;
  if (k0 >= K) return;
  const float* src = args.src[e];
  ushort* dst = args.dst[e];
  const int n0 = blockIdx.y * 32;
  const int tx = threadIdx.x & 31;
  const int ty = threadIdx.x >> 5;
#pragma unroll
  for (int r = 0; r < 4; ++r) t[ty + 8 * r][tx] = src[(size_t)(k0 + ty + 8 * r) * 256 + n0 + tx];
  __syncthreads();
#pragma unroll
  for (int r = 0; r < 4; ++r) dst[(size_t)(n0 + ty + 8 * r) * K + k0 + tx] = f2b(t[tx][ty + 8 * r]);
}

// ---------------- aggregation: S=self+neighbors (bf16), hd=deg*self (bf16), degf ----------------
__global__ __launch_bounds__(256) void k_aggregate(const ushort* __restrict__ h, const int* __restrict__ rowptr,
                                                   const int* __restrict__ col, ushort* __restrict__ S,
                                                   ushort* __restrict__ hd, float* __restrict__ degf, int n) {
  int node = blockIdx.x * 4 + (threadIdx.x >> 6);
  if (node >= n) return;
  int lane = threadIdx.x & 63;
  const ushort4* h4 = (const ushort4*)h;
  size_t base = (size_t)node * 64 + lane;
  ushort4 self = h4[base];
  float a0 = b2f(self.x), a1 = b2f(self.y), a2 = b2f(self.z), a3 = b2f(self.w);
  float s0 = a0, s1 = a1, s2 = a2, s3 = a3;
  int beg = rowptr[node], end = rowptr[node + 1];
  int p = beg;
  for (; p + 4 <= end; p += 4) {
    int j0 = col[p], j1 = col[p + 1], j2 = col[p + 2], j3 = col[p + 3];
    ushort4 v0 = h4[(size_t)j0 * 64 + lane];
    ushort4 v1 = h4[(size_t)j1 * 64 + lane];
    ushort4 v2 = h4[(size_t)j2 * 64 + lane];
    ushort4 v3 = h4[(size_t)j3 * 64 + lane];
    s0 += b2f(v0.x) + b2f(v1.x) + b2f(v2.x) + b2f(v3.x);
    s1 += b2f(v0.y) + b2f(v1.y) + b2f(v2.y) + b2f(v3.y);
    s2 += b2f(v0.z) + b2f(v1.z) + b2f(v2.z) + b2f(v3.z);
    s3 += b2f(v0.w) + b2f(v1.w) + b2f(v2.w) + b2f(v3.w);
  }
  for (; p < end; ++p) {
    int j = col[p];
    ushort4 v = h4[(size_t)j * 64 + lane];
    s0 += b2f(v.x); s1 += b2f(v.y); s2 += b2f(v.z); s3 += b2f(v.w);
  }
  float deg = (float)(end - beg + 1);
  ushort4 so; so.x = f2b(s0); so.y = f2b(s1); so.z = f2b(s2); so.w = f2b(s3);
  ((ushort4*)S)[base] = so;
  ushort4 ho; ho.x = f2b(deg * a0); ho.y = f2b(deg * a1); ho.z = f2b(deg * a2); ho.w = f2b(deg * a3);
  ((ushort4*)hd)[base] = ho;
  if (lane == 0) degf[node] = deg;
}

// ---------------- fused multi-layer MLP over a 128-row panel ----------------
// Block: 512 thr (8 waves, 2m x 4n; wave tile 64x64), output width fixed 256.
// Layer 0: A staged from global (dual-pass if DUAL: acc += A0@W0^T then += A1@W0b^T),
//          rowscale deg on bias if DUAL. Layers >=1: A read from LDS act buffer.
// act buffer [128][264] ushort (+8 pad per row -> 2-way max bank aliasing on b128 reads).
// B streamed double-buffered via global_load_lds w=16 with XOR k-slot source swizzle (rule #21).
struct MLPArgs {
  const ushort* A0;
  const ushort* A1;        // second A for dual layer-0 (or null)
  const ushort* W0b;       // second-pass B base for layer 0 (or null)
  const ushort* W[5];
  const float* bias[5];
  const float* degf;       // rowscale for layer-0 bias (DUAL only)
  ushort* out;
  int ldw0;
  int actf[5];
};

template <int NL, int K0, bool DUAL>
__global__ __launch_bounds__(512, 2) void k_mlp(MLPArgs args, int M) {
  __shared__ ushort act[128 * 264];
  __shared__ __align__(16) ushort As[2][128 * 32];
  __shared__ __align__(16) ushort Bs[2][256 * 32];
  __shared__ float degs[128];

  const int m0 = blockIdx.x * 128;
  const int tid = threadIdx.x;
  const int lane = tid & 63;
  const int wid = tid >> 6;
  const int wm = wid >> 2;   // 0..1
  const int wn = wid & 3;    // 0..3
  const int rl = lane & 15;
  const int kg = lane >> 4;

  if (DUAL) {
    if (tid < 128) {
      int rr = m0 + tid; if (rr > M - 1) rr = M - 1;
      degs[tid] = args.degf[rr];
    }
  }

  // staging slot math (identical to the verified round-6 GEMM)
  const int sl = tid & 3;
  const int s_row = tid >> 2;                 // A slot row 0..127 / B slot-1 row
  const int s_kg = sl ^ ((s_row >> 1) & 3);
  const int b2_row = (tid + 512) >> 2;        // B slot-2 row 128..255
  const int b2_kg = sl ^ ((b2_row >> 1) & 3);
  int ga = m0 + s_row; if (ga > M - 1) ga = M - 1;

#define STAGE_A(buf, Ap, k0s)                                                            \
  {                                                                                      \
    const ushort* sa_ = (Ap) + (size_t)ga * K0 + (k0s) + s_kg * 8;                       \
    __builtin_amdgcn_global_load_lds(                                                    \
        (const __attribute__((address_space(1))) void*)sa_,                              \
        (__attribute__((address_space(3))) void*)&As[buf][tid * 8], 16, 0, 0);           \
  }
#define STAGE_B(buf, Wp, ldw, k0s)                                                       \
  {                                                                                      \
    const ushort* s1_ = (Wp) + (size_t)s_row * (ldw) + (k0s) + s_kg * 8;                 \
    const ushort* s2_ = (Wp) + (size_t)b2_row * (ldw) + (k0s) + b2_kg * 8;               \
    __builtin_amdgcn_global_load_lds(                                                    \
        (const __attribute__((address_space(1))) void*)s1_,                              \
        (__attribute__((address_space(3))) void*)&Bs[buf][tid * 8], 16, 0, 0);           \
    __builtin_amdgcn_global_load_lds(                                                    \
        (const __attribute__((address_space(1))) void*)s2_,                              \
        (__attribute__((address_space(3))) void*)&Bs[buf][(tid + 512) * 8], 16, 0, 0);   \
  }

  // fragment addressing precompute
  int rr_[4], sA_[4], rn_[4], sB_[4];
#pragma unroll
  for (int fm = 0; fm < 4; ++fm) {
    rr_[fm] = wm * 64 + fm * 16 + rl;
    sA_[fm] = kg ^ ((rr_[fm] >> 1) & 3);
  }
#pragma unroll
  for (int fn = 0; fn < 4; ++fn) {
    rn_[fn] = wn * 64 + fn * 16 + rl;
    sB_[fn] = kg ^ ((rn_[fn] >> 1) & 3);
  }

  f32x4 acc[4][4];

  // epilogue helper: write leaky(acc + rs*bias) to act LDS or global out
  auto epilogue = [&](int L, bool toGlobal) {
    const float* bp = args.bias[L];
    const int af_ = args.actf[L];
#pragma unroll
    for (int fn = 0; fn < 4; ++fn) {
      int c = wn * 64 + fn * 16 + rl;
      float bv = bp[c];
#pragma unroll
      for (int fm = 0; fm < 4; ++fm) {
        int lrow0 = wm * 64 + fm * 16 + kg * 4;
#pragma unroll
        for (int rg = 0; rg < 4; ++rg) {
          int lrow = lrow0 + rg;
          float rs = (DUAL && L == 0) ? degs[lrow] : 1.0f;
          float v = acc[fm][fn][rg] + rs * bv;
          if (af_) v = leaky(v);
          if (toGlobal) {
            int grow = m0 + lrow;
            if (grow < M) args.out[(size_t)grow * 256 + c] = f2b(v);
          } else {
            act[lrow * 264 + c] = f2b(v);
          }
        }
      }
    }
  };

  // ---------- layer 0: A from global ----------
  constexpr int KS0 = K0 >> 5;
  constexpr int NT0 = DUAL ? 2 * KS0 : KS0;
#pragma unroll
  for (int i = 0; i < 4; ++i)
#pragma unroll
    for (int j = 0; j < 4; ++j) acc[i][j] = (f32x4)(0.f);

  STAGE_A(0, args.A0, 0);
  STAGE_B(0, args.W[0], args.ldw0, 0);
  __syncthreads();

#pragma unroll
  for (int t = 0; t < NT0; ++t) {
    if (t + 1 < NT0) {
      const int tp = t + 1;
      const int pass = DUAL ? (tp >= KS0 ? 1 : 0) : 0;
      const int k0s = (tp - pass * KS0) << 5;
      const ushort* Ap = pass ? args.A1 : args.A0;
      const ushort* Wp = pass ? args.W0b : args.W[0];
      STAGE_A(tp & 1, Ap, k0s);
      STAGE_B(tp & 1, Wp, args.ldw0, k0s);
    } else {
      STAGE_B(0, args.W[1], 256, 0);  // prefetch layer-1 step 0 (Bs[0] free: last read t=NT0-2)
    }
    const ushort* bA = &As[t & 1][0];
    const ushort* bB = &Bs[t & 1][0];
    bf16x8 afr[4], bfr[4];
#pragma unroll
    for (int fm = 0; fm < 4; ++fm) afr[fm] = *(const bf16x8*)&bA[rr_[fm] * 32 + sA_[fm] * 8];
#pragma unroll
    for (int fn = 0; fn < 4; ++fn) bfr[fn] = *(const bf16x8*)&bB[rn_[fn] * 32 + sB_[fn] * 8];
#pragma unroll
    for (int fm = 0; fm < 4; ++fm)
#pragma unroll
      for (int fn = 0; fn < 4; ++fn)
        acc[fm][fn] = __builtin_amdgcn_mfma_f32_16x16x32_bf16(afr[fm], bfr[fn], acc[fm][fn], 0, 0, 0);
    __syncthreads();
  }
  epilogue(0, NL == 1);
  __syncthreads();  // act visible to all waves

  // ---------- layers 1..NL-1: A from act LDS ----------
  for (int L = 1; L < NL; ++L) {
#pragma unroll
    for (int i = 0; i < 4; ++i)
#pragma unroll
      for (int j = 0; j < 4; ++j) acc[i][j] = (f32x4)(0.f);
#pragma unroll
    for (int t = 0; t < 8; ++t) {
      if (t < 7) {
        STAGE_B((t + 1) & 1, args.W[L], 256, (t + 1) * 32);
      } else if (L + 1 < NL) {
        STAGE_B(0, args.W[L + 1], 256, 0);
      }
      const ushort* bB = &Bs[t & 1][0];
      bf16x8 afr[4], bfr[4];
#pragma unroll
      for (int fm = 0; fm < 4; ++fm) afr[fm] = *(const bf16x8*)&act[rr_[fm] * 264 + t * 32 + kg * 8];
#pragma unroll
      for (int fn = 0; fn < 4; ++fn) bfr[fn] = *(const bf16x8*)&bB[rn_[fn] * 32 + sB_[fn] * 8];
#pragma unroll
      for (int fm = 0; fm < 4; ++fm)
#pragma unroll
        for (int fn = 0; fn < 4; ++fn)
          acc[fm][fn] = __builtin_amdgcn_mfma_f32_16x16x32_bf16(afr[fm], bfr[fn], acc[fm][fn], 0, 0, 0);
      __syncthreads();
    }
    if (L == NL - 1) {
      epilogue(L, true);
    } else {
      epilogue(L, false);
      __syncthreads();
    }
  }
#undef STAGE_A
#undef STAGE_B
}

// ---------------- decoder layer ----------------
__global__ __launch_bounds__(256) void k_dec_layer(
    const float* __restrict__ A, const float* __restrict__ W,
    const float* __restrict__ bias, float* __restrict__ out,
    int K, int N, int act)
{
  __shared__ float a[768];
  __shared__ float red[8][64];
  const int g = blockIdx.y;
  const int cols = (N >= 64) ? 64 : 32;
  const int segs = 256 / cols;
  const int t = threadIdx.x;
  const int col = t % cols, seg = t / cols;
  const int c = blockIdx.x * cols + col;
  for (int i = t; i < K; i += 256) a[i] = A[(size_t)g * K + i];
  __syncthreads();
  const int kper = K / segs;
  const int k0 = seg * kper;
  float p = 0.f;
#pragma unroll 8
  for (int k = k0; k < k0 + kper; ++k) p += a[k] * W[(size_t)k * N + c];
  red[seg][col] = p;
  __syncthreads();
  if (seg == 0) {
    float s = bias[c];
    for (int i = 0; i < segs; ++i) s += red[i][col];
    out[(size_t)g * N + c] = act ? leaky(s) : s;
  }
}

// ---------------- pooling ----------------
__global__ __launch_bounds__(256) void k_pool1(const ushort* __restrict__ h, const int* __restrict__ gstart,
                                               const int* __restrict__ gcnt, float* __restrict__ psum,
                                               float* __restrict__ pmax) {
  int g = blockIdx.x >> 4;
  int cch = blockIdx.x & 15;
  int t = threadIdx.x;
  int len = gcnt[g];
  int s0 = gstart[g];
  int chunk = (len + 15) >> 4;
  int i0 = s0 + cch * chunk;
  int i1 = min(i0 + chunk, s0 + len);
  float s = 0.f;
  float m = -3.402823466e+38f;
  for (int i = i0; i < i1; ++i) {
    float v = b2f(h[(size_t)i * HID + t]);
    s += v;
    m = fmaxf(m, v);
  }
  psum[(size_t)blockIdx.x * HID + t] = s;
  pmax[(size_t)blockIdx.x * HID + t] = m;
}

__global__ __launch_bounds__(256) void k_pool2(const float* __restrict__ psum, const float* __restrict__ pmax,
                                               const int* __restrict__ gcnt, float* __restrict__ pooled) {
  int g = blockIdx.x;
  int t = threadIdx.x;
  float s = 0.f, m = -3.402823466e+38f;
  for (int cch = 0; cch < 16; ++cch) {
    s += psum[(size_t)(g * 16 + cch) * HID + t];
    m = fmaxf(m, pmax[(size_t)(g * 16 + cch) * HID + t]);
  }
  float cf = (float)gcnt[g];
  pooled[g * 3 * HID + t] = s / fmaxf(cf, 1.f);
  pooled[g * 3 * HID + HID + t] = m;
  pooled[g * 3 * HID + 2 * HID + t] = s;
}

// ---------------- launch ----------------
extern "C" void kernel_launch(void* const* d_in, const int* in_sizes, int n_in,
                              void* d_out, int out_size, void* d_ws, size_t ws_size,
                              hipStream_t stream) {
  const float* x        = (const float*)d_in[0];
  const int*   ei       = (const int*)d_in[1];
  const int*   batch    = (const int*)d_in[2];
  const float* enc_Win  = (const float*)d_in[3];
  const float* enc_bin  = (const float*)d_in[4];
  const float* enc_Wh   = (const float*)d_in[5];
  const float* enc_bh   = (const float*)d_in[6];
  const float* enc_Wout = (const float*)d_in[7];
  const float* enc_bout = (const float*)d_in[8];
  const float* edge_W   = (const float*)d_in[9];
  const float* edge_b   = (const float*)d_in[10];
  const float* proc_Win = (const float*)d_in[11];
  const float* proc_bin = (const float*)d_in[12];
  const float* proc_Wh  = (const float*)d_in[13];
  const float* proc_bh  = (const float*)d_in[14];
  const float* proc_Wout= (const float*)d_in[15];
  const float* proc_bout= (const float*)d_in[16];
  const float* dec_Win  = (const float*)d_in[17];
  const float* dec_bin  = (const float*)d_in[18];
  const float* dec_Wh   = (const float*)d_in[19];
  const float* dec_bh   = (const float*)d_in[20];
  const float* dec_Wout = (const float*)d_in[21];
  const float* dec_bout = (const float*)d_in[22];

  const int n  = in_sizes[0] / 128;  // 20000
  const int ne = in_sizes[1] / 2;    // 160000
  const int H = HID;

  char* p = (char*)d_ws;
  auto alloc = [&](size_t bytes) -> char* {
    char* r = p;
    p += (bytes + 255) & ~(size_t)255;
    return r;
  };
  ushort* hb1   = (ushort*)alloc((size_t)n * H * 2);
  ushort* Sb    = (ushort*)alloc((size_t)n * H * 2);
  ushort* hdb   = (ushort*)alloc((size_t)n * H * 2);
  ushort* xb    = (ushort*)alloc((size_t)n * 128 * 2);
  ushort* w_enc_in  = (ushort*)alloc((size_t)256 * 128 * 2);
  ushort* w_enc_h0  = (ushort*)alloc((size_t)256 * 256 * 2);
  ushort* w_enc_h1  = (ushort*)alloc((size_t)256 * 256 * 2);
  ushort* w_enc_out = (ushort*)alloc((size_t)256 * 256 * 2);
  ushort* w_proc_in  = (ushort*)alloc((size_t)256 * 256 * 2);
  ushort* w_proc_h0  = (ushort*)alloc((size_t)256 * 256 * 2);
  ushort* w_proc_h1  = (ushort*)alloc((size_t)256 * 256 * 2);
  ushort* w_proc_out = (ushort*)alloc((size_t)256 * 256 * 2);
  ushort* w_edge     = (ushort*)alloc((size_t)256 * 512 * 2);
  float* degf   = (float*)alloc((size_t)n * 4);
  float* pooled = (float*)alloc((size_t)NGRAPH * 3 * H * 4);
  float* psum   = (float*)alloc((size_t)256 * H * 4);
  float* pmax   = (float*)alloc((size_t)256 * H * 4);
  float* db0    = (float*)alloc((size_t)NGRAPH * H * 4);
  float* db1    = (float*)alloc((size_t)NGRAPH * H * 4);
  int* cnt    = (int*)alloc((size_t)n * 4);
  int* rowptr = (int*)alloc((size_t)(n + 1) * 4);
  int* cursor = (int*)alloc((size_t)n * 4);
  int* gstart = (int*)alloc((size_t)(NGRAPH + 1) * 4);
  int* gcnt   = (int*)alloc((size_t)NGRAPH * 4);
  int* colv   = (int*)alloc((size_t)ne * 4);

  const int* srcI = ei;
  const int* dstI = ei + ne;

  dim3 blk(256);

  // fused weight conversions (transpose to [N=256][K] bf16)
  WconvArgs wa;
  wa.src[0] = enc_Win;             wa.dst[0] = w_enc_in;   wa.K[0] = 128;
  wa.src[1] = enc_Wh;              wa.dst[1] = w_enc_h0;   wa.K[1] = 256;
  wa.src[2] = enc_Wh + 65536;      wa.dst[2] = w_enc_h1;   wa.K[2] = 256;
  wa.src[3] = enc_Wout;            wa.dst[3] = w_enc_out;  wa.K[3] = 256;
  wa.src[4] = proc_Win;            wa.dst[4] = w_proc_in;  wa.K[4] = 256;
  wa.src[5] = proc_Wh;             wa.dst[5] = w_proc_h0;  wa.K[5] = 256;
  wa.src[6] = proc_Wh + 65536;     wa.dst[6] = w_proc_h1;  wa.K[6] = 256;
  wa.src[7] = proc_Wout;           wa.dst[7] = w_proc_out; wa.K[7] = 256;
  wa.src[8] = edge_W;              wa.dst[8] = w_edge;     wa.K[8] = 512;
  k_wconv_all<<<dim3(16, 8, 9), blk, 0, stream>>>(wa);
  k_f2b<<<dim3((n * 128 / 4 + 255) / 256), blk, 0, stream>>>(x, xb, n * 128);

  // CSR by destination + per-graph bounds
  k_zero_i32<<<dim3((n + 255) / 256), blk, 0, stream>>>(cnt, n);
  k_hist<<<dim3((ne + 255) / 256), blk, 0, stream>>>(dstI, cnt, ne);
  k_scan<<<1, 1024, 0, stream>>>(cnt, rowptr, cursor, n);
  k_gbounds<<<1, 64, 0, stream>>>(batch, n, gstart, gcnt);
  k_scatter<<<dim3((ne + 255) / 256), blk, 0, stream>>>(srcI, dstI, cursor, colv, ne);

  const int npanel = (n + 127) / 128;  // 157
  dim3 mblk(512);

  // fused encoder: 4 layers, one kernel
  MLPArgs ea = {};
  ea.A0 = xb; ea.A1 = nullptr; ea.W0b = nullptr;
  ea.W[0] = w_enc_in; ea.W[1] = w_enc_h0; ea.W[2] = w_enc_h1; ea.W[3] = w_enc_out;
  ea.bias[0] = enc_bin; ea.bias[1] = enc_bh; ea.bias[2] = enc_bh + 256; ea.bias[3] = enc_bout;
  ea.degf = nullptr; ea.out = hb1; ea.ldw0 = 128;
  ea.actf[0] = 1; ea.actf[1] = 1; ea.actf[2] = 1; ea.actf[3] = 0;
  k_mlp<4, 128, false><<<dim3(npanel), mblk, 0, stream>>>(ea, n);

  // fused proc: edge (dual-A) + 4 proc layers, one kernel per MP round
  MLPArgs pa = {};
  pa.A0 = hdb; pa.A1 = Sb; pa.W0b = w_edge + 256;
  pa.W[0] = w_edge; pa.W[1] = w_proc_in; pa.W[2] = w_proc_h0; pa.W[3] = w_proc_h1; pa.W[4] = w_proc_out;
  pa.bias[0] = edge_b; pa.bias[1] = proc_bin; pa.bias[2] = proc_bh; pa.bias[3] = proc_bh + 256; pa.bias[4] = proc_bout;
  pa.degf = degf; pa.out = hb1; pa.ldw0 = 512;
  pa.actf[0] = 0; pa.actf[1] = 1; pa.actf[2] = 1; pa.actf[3] = 1; pa.actf[4] = 0;

  for (int r = 0; r < 4; ++r) {
    k_aggregate<<<dim3((n + 3) / 4), blk, 0, stream>>>(hb1, rowptr, colv, Sb, hdb, degf, n);
    k_mlp<5, 256, true><<<dim3(npanel), mblk, 0, stream>>>(pa, n);
  }

  // pooling
  k_pool1<<<dim3(NGRAPH * 16), blk, 0, stream>>>(hb1, gstart, gcnt, psum, pmax);
  k_pool2<<<dim3(NGRAPH), blk, 0, stream>>>(psum, pmax, gcnt, pooled);

  // decoder
  k_dec_layer<<<dim3(4, NGRAPH), blk, 0, stream>>>(pooled, dec_Win, dec_bin, db0, 768, 256, 1);
  k_dec_layer<<<dim3(4, NGRAPH), blk, 0, stream>>>(db0, dec_Wh, dec_bh, db1, 256, 256, 1);
  k_dec_layer<<<dim3(4, NGRAPH), blk, 0, stream>>>(db1, dec_Wh + 65536, dec_bh + 256, db0, 256, 256, 1);
  k_dec_layer<<<dim3(1, NGRAPH), blk, 0, stream>>>(db0, dec_Wout, dec_bout, (float*)d_out, 256, 32, 0);
}